// Round 5
// baseline (341.123 us; speedup 1.0000x reference)
//
#include <hip/hip_runtime.h>
#include <hip/hip_bf16.h>

static constexpr int H = 16;   // hidden channels
static constexpr int C = 16;   // num classes

static __device__ inline unsigned short f2bf(float x) {
    __hip_bfloat16 b = __float2bfloat16(x);
    return *reinterpret_cast<unsigned short*>(&b);
}
// bf16 pair unpack without cvt: bf16 in low/high half of a dword -> f32 by bit placement
static __device__ inline float bflo(unsigned u) { return __uint_as_float(u << 16); }
static __device__ inline float bfhi(unsigned u) { return __uint_as_float(u & 0xffff0000u); }

// ---------------- CSR build: degree histogram --------------------------------------
__global__ void k_deg(const int* __restrict__ dstv, int* __restrict__ deg, int E) {
    int e = blockIdx.x * blockDim.x + threadIdx.x;
    if (e < E) atomicAdd(&deg[dstv[e]], 1);
}

// ---------------- CSR build: scan stage 1 (local exclusive prefix, 1024/block) -----
__global__ void k_scan1(const int* __restrict__ deg, int* __restrict__ cursor,
                        int* __restrict__ bsum, int N) {
    __shared__ int sh[256];
    int tid = threadIdx.x;
    int base = blockIdx.x * 1024 + tid * 4;
    int d0 = (base + 0 < N) ? deg[base + 0] : 0;
    int d1 = (base + 1 < N) ? deg[base + 1] : 0;
    int d2 = (base + 2 < N) ? deg[base + 2] : 0;
    int d3 = (base + 3 < N) ? deg[base + 3] : 0;
    int t = d0 + d1 + d2 + d3;
    sh[tid] = t;
    __syncthreads();
    for (int off = 1; off < 256; off <<= 1) {   // Hillis-Steele inclusive
        int v = (tid >= off) ? sh[tid - off] : 0;
        __syncthreads();
        sh[tid] += v;
        __syncthreads();
    }
    int excl = sh[tid] - t;
    if (tid == 255) bsum[blockIdx.x] = sh[255];
    int run = excl;
    if (base + 0 < N) { cursor[base + 0] = run; run += d0; }
    if (base + 1 < N) { cursor[base + 1] = run; run += d1; }
    if (base + 2 < N) { cursor[base + 2] = run; run += d2; }
    if (base + 3 < N) { cursor[base + 3] = run; run += d3; }
}

// ---------------- CSR build: scan stage 2 (block bases, tiny serial) ---------------
__global__ void k_scan2(const int* __restrict__ bsum, int* __restrict__ bbase, int nb) {
    if (threadIdx.x == 0 && blockIdx.x == 0) {
        int acc = 0;
        for (int i = 0; i < nb; ++i) { bbase[i] = acc; acc += bsum[i]; }
    }
}

// ---------------- CSR build: scan stage 3 (add block base) -------------------------
__global__ void k_scan3(int* __restrict__ cursor, const int* __restrict__ bbase, int N) {
    int i = blockIdx.x * blockDim.x + threadIdx.x;
    if (i < N) cursor[i] += bbase[i >> 10];
}

// ---------------- CSR build: fill slots with packed (r<<17)|src --------------------
__global__ void k_fill(const int* __restrict__ srcv, const int* __restrict__ dstv,
                       const int* __restrict__ etv, int* __restrict__ cursor,
                       unsigned* __restrict__ csr, int E) {
    int e = blockIdx.x * blockDim.x + threadIdx.x;
    if (e >= E) return;
    int d = dstv[e];
    int pos = atomicAdd(&cursor[d], 1);
    csr[pos] = ((unsigned)etv[e] << 17) | (unsigned)srcv[e];
}
// after k_fill: cursor[d] == row_end(d); row_start(d) == cursor[d] - deg[d]

// ---------------- prep: [W2; root2] -> bf16, transposed to [R+1][C][K] -------------
__global__ void k0_cast(const float* __restrict__ W2, const float* __restrict__ root2,
                        unsigned short* __restrict__ w2t, int R) {
    int i = blockIdx.x * blockDim.x + threadIdx.x;
    if (i >= (R + 1) * 256) return;
    int r = i >> 8;
    int kc = i & 255;
    int k = kc >> 4, c = kc & 15;
    float v = (r < R) ? W2[(size_t)r * 256 + k * 16 + c] : root2[k * 16 + c];
    w2t[(r << 8) + (c << 4) + k] = f2bf(v);
}

// ---------------- Layer 1 (pull, atomic-free): h1 = relu(root1 + sum W1[r,s] + b1) -
// 16 lanes = 16 channels per dst; register accumulate; fused finalize; bf16 store.
__global__ void k1_csr(const unsigned* __restrict__ csr, const int* __restrict__ cursor,
                       const int* __restrict__ deg, const float* __restrict__ W1,
                       const float* __restrict__ root1, const float* __restrict__ bias1,
                       unsigned short* __restrict__ h1bf, int N) {
    int t = blockIdx.x * blockDim.x + threadIdx.x;
    int d = t >> 4, c = t & 15;
    if (d >= N) return;
    int end = cursor[d];
    int start = end - deg[d];
    float acc = root1[(size_t)d * 16 + c] + bias1[c];
    for (int i = start; i < end; ++i) {
        unsigned u = csr[i];
        int s = u & 0x1ffff;
        int r = u >> 17;
        acc += W1[((size_t)r * N + s) * 16 + c];
    }
    h1bf[(size_t)d * 16 + c] = f2bf(fmaxf(acc, 0.f));
}

// ---------------- Layer 2 (pull, atomic-free) + fused log_softmax ------------------
// acc_c = bias2_c + sum_edges h1[s] . w2t[r][c][:] + h1[d] . w2t[R][c][:] (root2)
__global__ void k3_csr(const unsigned* __restrict__ csr, const int* __restrict__ cursor,
                       const int* __restrict__ deg, const unsigned short* __restrict__ h1bf,
                       const unsigned short* __restrict__ w2t, const float* __restrict__ bias2,
                       float* __restrict__ out, int N, int R) {
    int t = blockIdx.x * blockDim.x + threadIdx.x;
    int d = t >> 4, c = t & 15;
    if (d >= N) return;
    int end = cursor[d];
    int start = end - deg[d];
    float acc = bias2[c];
    for (int i = start; i <= end; ++i) {      // i==end -> virtual root2 edge (s=d, r=R)
        int s, r;
        if (i < end) {
            unsigned u = csr[i];
            s = (int)(u & 0x1ffff);
            r = (int)(u >> 17);
        } else {
            s = d; r = R;
        }
        const uint4* hp = (const uint4*)(h1bf + (size_t)s * 16);   // 32B row, broadcast
        uint4 hlo = hp[0], hhi = hp[1];
        const uint4* wp = (const uint4*)(w2t + ((size_t)r << 8) + (c << 4));
        uint4 wlo = wp[0], whi = wp[1];
        acc += bflo(hlo.x) * bflo(wlo.x) + bfhi(hlo.x) * bfhi(wlo.x);
        acc += bflo(hlo.y) * bflo(wlo.y) + bfhi(hlo.y) * bfhi(wlo.y);
        acc += bflo(hlo.z) * bflo(wlo.z) + bfhi(hlo.z) * bfhi(wlo.z);
        acc += bflo(hlo.w) * bflo(wlo.w) + bfhi(hlo.w) * bfhi(wlo.w);
        acc += bflo(hhi.x) * bflo(whi.x) + bfhi(hhi.x) * bfhi(whi.x);
        acc += bflo(hhi.y) * bflo(whi.y) + bfhi(hhi.y) * bfhi(whi.y);
        acc += bflo(hhi.z) * bflo(whi.z) + bfhi(hhi.z) * bfhi(whi.z);
        acc += bflo(hhi.w) * bflo(whi.w) + bfhi(hhi.w) * bfhi(whi.w);
    }
    // log_softmax across the 16 lanes of this dst-group
    float m = acc;
    for (int off = 8; off; off >>= 1) m = fmaxf(m, __shfl_xor(m, off, 16));
    float ex = __expf(acc - m);
    float se = ex;
    for (int off = 8; off; off >>= 1) se += __shfl_xor(se, off, 16);
    out[(size_t)d * 16 + c] = acc - m - __logf(se);
}

extern "C" void kernel_launch(void* const* d_in, const int* in_sizes, int n_in,
                              void* d_out, int out_size, void* d_ws, size_t ws_size,
                              hipStream_t stream) {
    const int*   edge_index   = (const int*)d_in[0];
    const int*   edge_type    = (const int*)d_in[1];
    const float* W1    = (const float*)d_in[3];
    const float* root1 = (const float*)d_in[4];
    const float* bias1 = (const float*)d_in[5];
    const float* W2    = (const float*)d_in[6];
    const float* root2 = (const float*)d_in[7];
    const float* bias2 = (const float*)d_in[8];
    float* out = (float*)d_out;

    const int E = in_sizes[0] / 2;
    const int N = in_sizes[4] / H;           // root1 is N*H
    const int R = in_sizes[2] / 2;           // tensor_slice is [R][2]
    const int* srcv = edge_index;
    const int* dstv = edge_index + E;

    // ws layout (16B-aligned blocks first):
    // csr [E u32] | h1bf [N*16 u16] | w2t [(R+1)*256 u16] | deg [N] | cursor [N] | bsum/bbase
    char* p = (char*)d_ws;
    unsigned* csr = (unsigned*)p;                 p += (size_t)E * 4;
    unsigned short* h1bf = (unsigned short*)p;    p += (size_t)N * 16 * 2;
    unsigned short* w2t = (unsigned short*)p;     p += (size_t)(R + 1) * 256 * 2;
    p = (char*)(((uintptr_t)p + 15) & ~(uintptr_t)15);
    int* deg = (int*)p;                           p += (size_t)N * 4;
    int* cursor = (int*)p;                        p += (size_t)N * 4;
    int* bsum = (int*)p;                          p += 256 * 4;
    int* bbase = (int*)p;

    const int B = 256;
    const int nb = (N + 1023) / 1024;

    hipMemsetAsync(deg, 0, (size_t)N * sizeof(int), stream);
    k_deg<<<(E + B - 1) / B, B, 0, stream>>>(dstv, deg, E);
    k_scan1<<<nb, B, 0, stream>>>(deg, cursor, bsum, N);
    k_scan2<<<1, 64, 0, stream>>>(bsum, bbase, nb);
    k_scan3<<<(N + B - 1) / B, B, 0, stream>>>(cursor, bbase, N);
    k_fill<<<(E + B - 1) / B, B, 0, stream>>>(srcv, dstv, edge_type, cursor, csr, E);
    k0_cast<<<((R + 1) * 256 + B - 1) / B, B, 0, stream>>>(W2, root2, w2t, R);

    int tN = N * 16;
    k1_csr<<<(tN + B - 1) / B, B, 0, stream>>>(csr, cursor, deg, W1, root1, bias1, h1bf, N);
    k3_csr<<<(tN + B - 1) / B, B, 0, stream>>>(csr, cursor, deg, h1bf, w2t, bias2, out, N, R);
}

// Round 6
// 197.124 us; speedup vs baseline: 1.7305x; 1.7305x over previous
//
#include <hip/hip_runtime.h>
#include <hip/hip_bf16.h>

static constexpr int H = 16;   // hidden channels
static constexpr int C = 16;   // num classes

typedef __attribute__((ext_vector_type(8))) short bf16x8;
typedef __attribute__((ext_vector_type(4))) float f32x4;

static __device__ inline unsigned short f2bf(float x) {
    __hip_bfloat16 b = __float2bfloat16(x);
    return *reinterpret_cast<unsigned short*>(&b);
}
static __device__ inline float bflo(unsigned u) { return __uint_as_float(u << 16); }
static __device__ inline float bfhi(unsigned u) { return __uint_as_float(u & 0xffff0000u); }
// packed bf16 atomic add (2 channels per dword) -- halves atomic-dword count
static __device__ inline void pk_atomic_bf16(unsigned short* addr, unsigned pk) {
    asm volatile("global_atomic_pk_add_bf16 %0, %1, off" :: "v"(addr), "v"(pk) : "memory");
}

// ---------------- Layer 1: acc1[dst] += bf16x2(W1[et, src]); 8 lanes x 4 edges -----
__global__ void k1_scatter(const int* __restrict__ srcv, const int* __restrict__ dstv,
                           const int* __restrict__ etv, const float* __restrict__ W1,
                           unsigned short* __restrict__ acc1, int E, int N) {
    int t = blockIdx.x * blockDim.x + threadIdx.x;
    int g = t >> 3;            // group of 4 edges
    int cp = t & 7;            // channel pair: channels 2cp, 2cp+1
    int e0 = g << 2;
    if (e0 >= E) return;
    int n = min(4, E - e0);
    int s[4], d[4], r[4];
#pragma unroll
    for (int i = 0; i < 4; ++i) {
        int e = e0 + ((i < n) ? i : 0);
        s[i] = srcv[e]; d[i] = dstv[e]; r[i] = etv[e];
    }
    float2 v[4];
#pragma unroll
    for (int i = 0; i < 4; ++i)
        v[i] = *(const float2*)(W1 + ((size_t)r[i] * N + (size_t)s[i]) * H + (cp << 1));
#pragma unroll
    for (int i = 0; i < 4; ++i)
        if (i < n) {
            unsigned pk = ((unsigned)f2bf(v[i].y) << 16) | f2bf(v[i].x);
            pk_atomic_bf16(acc1 + ((size_t)d[i] << 4) + (cp << 1), pk);
        }
}

// ---------------- h1 = relu(root1 + acc1 + bias1); f32 + bf16 copies ---------------
__global__ void k2_fin1(const float* __restrict__ root1, const float* __restrict__ bias1,
                        const unsigned short* __restrict__ acc1, float* __restrict__ h1,
                        unsigned int* __restrict__ h1bf, int total4) {
    int i = blockIdx.x * blockDim.x + threadIdx.x;
    if (i >= total4) return;
    float4 rv = ((const float4*)root1)[i];
    uint2 av = ((const uint2*)acc1)[i];
    float4 bv = ((const float4*)bias1)[i & 3];
    float4 o;
    o.x = fmaxf(rv.x + bflo(av.x) + bv.x, 0.0f);
    o.y = fmaxf(rv.y + bfhi(av.x) + bv.y, 0.0f);
    o.z = fmaxf(rv.z + bflo(av.y) + bv.z, 0.0f);
    o.w = fmaxf(rv.w + bfhi(av.y) + bv.w, 0.0f);
    ((float4*)h1)[i] = o;
    uint2 p;
    p.x = ((unsigned)f2bf(o.y) << 16) | f2bf(o.x);
    p.y = ((unsigned)f2bf(o.w) << 16) | f2bf(o.z);
    ((uint2*)h1bf)[i] = p;
}

// ---------------- prep: per-relation 16-edge chunk offsets (exclusive scan) --------
__global__ void k0_prep(const int* __restrict__ ts, int* __restrict__ chunk_off, int R) {
    if (blockIdx.x == 0 && threadIdx.x == 0) {
        int acc = 0;
        for (int r = 0; r < R; ++r) {
            chunk_off[r] = acc;
            int cnt = ts[2 * r + 1] - ts[2 * r];
            acc += (cnt + 15) >> 4;
        }
        chunk_off[R] = acc;
    }
}

// ---------------- prep: W2 -> bf16, transposed to [R][C][H] ------------------------
__global__ void k0_cast(const float* __restrict__ W2, unsigned short* __restrict__ w2t,
                        int total /* R*H*C */) {
    int i = blockIdx.x * blockDim.x + threadIdx.x;
    if (i >= total) return;
    int r = i >> 8;
    int kc = i & 255;
    int k = kc >> 4;
    int c = kc & 15;
    w2t[(r << 8) + (c << 4) + k] = f2bf(W2[i]);
}

// ---------------- Layer 2 via MFMA: one wave = 16 edges of ONE relation ------------
// D[16x16] = A(h1bf rows, gathered) x B(W2^T[r]), K=32 zero-padded.
// D: col = l&15, row = (l>>4)*4 + reg. Adjacent cols live in adjacent lanes ->
// even lanes pack (c,c+1) via shfl_xor(1) and issue ONE pk-bf16 atomic per row.
__global__ void k3_mfma(const int* __restrict__ srcv, const int* __restrict__ dstv,
                        const int* __restrict__ ts, const int* __restrict__ chunk_off,
                        const unsigned short* __restrict__ h1bf,
                        const unsigned short* __restrict__ w2t,
                        unsigned short* __restrict__ acc2, int R) {
    int w = (blockIdx.x * blockDim.x + threadIdx.x) >> 6;
    int l = threadIdx.x & 63;
    int total = chunk_off[R];
    if (w >= total) return;
    int lo = 0, hi = R;
    while (hi - lo > 1) {
        int mid = (lo + hi) >> 1;
        if (chunk_off[mid] <= w) lo = mid; else hi = mid;
    }
    int r = lo;
    int e0 = ts[2 * r] + ((w - chunk_off[r]) << 4);
    int eend = ts[2 * r + 1];
    int n_e = min(16, eend - e0);

    int rowA = l & 15;
    int kg = l >> 4;
    int eA = e0 + min(rowA, n_e - 1);
    int s = srcv[eA];

    bf16x8 a = {0, 0, 0, 0, 0, 0, 0, 0};
    bf16x8 b = {0, 0, 0, 0, 0, 0, 0, 0};
    if (kg < 2) {
        a = *(const bf16x8*)(h1bf + ((size_t)s << 4) + (kg << 3));
        b = *(const bf16x8*)(w2t + ((size_t)r << 8) + (rowA << 4) + (kg << 3));
    }
    f32x4 d = {0.f, 0.f, 0.f, 0.f};
    d = __builtin_amdgcn_mfma_f32_16x16x32_bf16(a, b, d, 0, 0, 0);

    int c = l & 15;
#pragma unroll
    for (int j = 0; j < 4; ++j) {
        float o = __shfl_xor(d[j], 1);          // neighbor column's value, same row
        int row = (kg << 2) + j;
        if (((l & 1) == 0) && row < n_e) {
            int dd = dstv[e0 + row];
            unsigned pk = ((unsigned)f2bf(o) << 16) | f2bf(d[j]);
            pk_atomic_bf16(acc2 + ((size_t)dd << 4) + c, pk);
        }
    }
}

// ---------------- h2 = h1 @ root2 + acc2 + bias2; row log_softmax ------------------
__global__ void k4_fin2(const float* __restrict__ h1, const unsigned short* __restrict__ acc2,
                        const float* __restrict__ root2, const float* __restrict__ bias2,
                        float* __restrict__ out, int N) {
    int n = blockIdx.x * blockDim.x + threadIdx.x;
    if (n >= N) return;
    const float* hr = h1 + (size_t)n * H;
    float h[16];
#pragma unroll
    for (int k = 0; k < 16; ++k) h[k] = hr[k];
    const uint4* ap = (const uint4*)(acc2 + (size_t)n * 16);
    uint4 a0 = ap[0], a1 = ap[1];
    float av[16] = {bflo(a0.x), bfhi(a0.x), bflo(a0.y), bfhi(a0.y),
                    bflo(a0.z), bfhi(a0.z), bflo(a0.w), bfhi(a0.w),
                    bflo(a1.x), bfhi(a1.x), bflo(a1.y), bfhi(a1.y),
                    bflo(a1.z), bfhi(a1.z), bflo(a1.w), bfhi(a1.w)};
    float* o = out + (size_t)n * C;
    float z[16];
#pragma unroll
    for (int c = 0; c < 16; ++c) {
        float acc = av[c] + bias2[c];
#pragma unroll
        for (int k = 0; k < 16; ++k) acc += h[k] * root2[k * C + c];
        z[c] = acc;
    }
    float m = z[0];
#pragma unroll
    for (int c = 1; c < 16; ++c) m = fmaxf(m, z[c]);
    float se = 0.f;
#pragma unroll
    for (int c = 0; c < 16; ++c) se += __expf(z[c] - m);
    float lse = m + __logf(se);
#pragma unroll
    for (int c = 0; c < 16; ++c) o[c] = z[c] - lse;
}

extern "C" void kernel_launch(void* const* d_in, const int* in_sizes, int n_in,
                              void* d_out, int out_size, void* d_ws, size_t ws_size,
                              hipStream_t stream) {
    const int*   edge_index   = (const int*)d_in[0];
    const int*   edge_type    = (const int*)d_in[1];
    const int*   tensor_slice = (const int*)d_in[2];
    const float* W1    = (const float*)d_in[3];
    const float* root1 = (const float*)d_in[4];
    const float* bias1 = (const float*)d_in[5];
    const float* W2    = (const float*)d_in[6];
    const float* root2 = (const float*)d_in[7];
    const float* bias2 = (const float*)d_in[8];
    float* out = (float*)d_out;

    const int E = in_sizes[0] / 2;
    const int N = in_sizes[4] / H;           // root1 is N*H
    const int R = in_sizes[2] / 2;           // tensor_slice is [R][2]
    const int* srcv = edge_index;
    const int* dstv = edge_index + E;

    // ws layout: acc1 bf16 [N*16] | h1 f32 [N*16] | h1bf u16 [N*16] | w2t u16 [R*256]
    //            | acc2 bf16 [N*16] | chunk_off int [R+1]
    char* p = (char*)d_ws;
    unsigned short* acc1 = (unsigned short*)p;   p += (size_t)N * 16 * 2;
    float* h1 = (float*)p;                       p += (size_t)N * 16 * 4;
    unsigned short* h1bf = (unsigned short*)p;   p += (size_t)N * 16 * 2;
    unsigned short* w2t = (unsigned short*)p;    p += (size_t)R * 256 * 2;
    unsigned short* acc2 = (unsigned short*)p;   p += (size_t)N * 16 * 2;
    int* chunk_off = (int*)p;

    hipMemsetAsync(acc1, 0, (size_t)N * 16 * 2, stream);
    hipMemsetAsync(acc2, 0, (size_t)N * 16 * 2, stream);

    const int B = 256;
    k0_prep<<<1, 64, 0, stream>>>(tensor_slice, chunk_off, R);
    k0_cast<<<(R * 256 + B - 1) / B, B, 0, stream>>>(W2, w2t, R * 256);
    // layer 1: 8 lanes x 4 edges per group
    long long g1 = ((long long)E + 3) / 4;
    long long t1 = g1 * 8;
    k1_scatter<<<(int)((t1 + B - 1) / B), B, 0, stream>>>(srcv, dstv, edge_type, W1, acc1, E, N);
    int total4 = N * H / 4;
    k2_fin1<<<(total4 + B - 1) / B, B, 0, stream>>>(root1, bias1, acc1, h1,
                                                    (unsigned int*)h1bf, total4);
    long long waves_ub = (long long)((E + 15) / 16) + R;
    long long thr = waves_ub * 64;
    k3_mfma<<<(int)((thr + B - 1) / B), B, 0, stream>>>(srcv, dstv, tensor_slice, chunk_off,
                                                        h1bf, w2t, acc2, R);
    k4_fin2<<<(N + B - 1) / B, B, 0, stream>>>(h1, acc2, root2, bias2, out, N);
}

// Round 7
// 192.564 us; speedup vs baseline: 1.7715x; 1.0237x over previous
//
#include <hip/hip_runtime.h>
#include <hip/hip_bf16.h>

static constexpr int H = 16;   // hidden channels
static constexpr int C = 16;   // num classes

typedef __attribute__((ext_vector_type(8))) short bf16x8;
typedef __attribute__((ext_vector_type(4))) float f32x4;

static __device__ inline unsigned short f2bf(float x) {
    __hip_bfloat16 b = __float2bfloat16(x);
    return *reinterpret_cast<unsigned short*>(&b);
}
static __device__ inline float bflo(unsigned u) { return __uint_as_float(u << 16); }
static __device__ inline float bfhi(unsigned u) { return __uint_as_float(u & 0xffff0000u); }
// packed bf16 atomic add (2 channels per dword)
static __device__ inline void pk_atomic_bf16(unsigned short* addr, unsigned pk) {
    asm volatile("global_atomic_pk_add_bf16 %0, %1, off" :: "v"(addr), "v"(pk) : "memory");
}

// ---------------- Layer 1: acc1[dst] += bf16x2(W1[et, src]); 8 lanes x 8 edges -----
__global__ void k1_scatter(const int* __restrict__ srcv, const int* __restrict__ dstv,
                           const int* __restrict__ etv, const float* __restrict__ W1,
                           unsigned short* __restrict__ acc1, int E, int N) {
    int t = blockIdx.x * blockDim.x + threadIdx.x;
    int g = t >> 3;            // group of 8 edges
    int cp = t & 7;            // channel pair: channels 2cp, 2cp+1
    int e0 = g << 3;
    if (e0 >= E) return;
    int n = min(8, E - e0);
    int s[8], d[8], r[8];
#pragma unroll
    for (int i = 0; i < 8; ++i) {
        int e = e0 + ((i < n) ? i : 0);
        s[i] = srcv[e]; d[i] = dstv[e]; r[i] = etv[e];
    }
    float2 v[8];
#pragma unroll
    for (int i = 0; i < 8; ++i)
        v[i] = *(const float2*)(W1 + ((size_t)r[i] * N + (size_t)s[i]) * H + (cp << 1));
#pragma unroll
    for (int i = 0; i < 8; ++i)
        if (i < n) {
            unsigned pk = ((unsigned)f2bf(v[i].y) << 16) | f2bf(v[i].x);
            pk_atomic_bf16(acc1 + ((size_t)d[i] << 4) + (cp << 1), pk);
        }
}

// ---------------- h1bf = bf16(relu(root1 + acc1 + bias1)) --------------------------
__global__ void k2_fin1(const float* __restrict__ root1, const float* __restrict__ bias1,
                        const unsigned short* __restrict__ acc1,
                        unsigned int* __restrict__ h1bf, int total4) {
    int i = blockIdx.x * blockDim.x + threadIdx.x;
    if (i >= total4) return;
    float4 rv = ((const float4*)root1)[i];
    uint2 av = ((const uint2*)acc1)[i];
    float4 bv = ((const float4*)bias1)[i & 3];
    float4 o;
    o.x = fmaxf(rv.x + bflo(av.x) + bv.x, 0.0f);
    o.y = fmaxf(rv.y + bfhi(av.x) + bv.y, 0.0f);
    o.z = fmaxf(rv.z + bflo(av.y) + bv.z, 0.0f);
    o.w = fmaxf(rv.w + bfhi(av.y) + bv.w, 0.0f);
    uint2 p;
    p.x = ((unsigned)f2bf(o.y) << 16) | f2bf(o.x);
    p.y = ((unsigned)f2bf(o.w) << 16) | f2bf(o.z);
    ((uint2*)h1bf)[i] = p;
}

// ---------------- prep: chunk offsets (serial, tiny) -------------------------------
__global__ void k0_prep(const int* __restrict__ ts, int* __restrict__ chunk_off, int R) {
    if (blockIdx.x == 0 && threadIdx.x == 0) {
        int acc = 0;
        for (int r = 0; r < R; ++r) {
            chunk_off[r] = acc;
            int cnt = ts[2 * r + 1] - ts[2 * r];
            acc += (cnt + 15) >> 4;
        }
        chunk_off[R] = acc;
    }
}

// ---------------- prep: chunk -> (e0, r, n) map (parallel) -------------------------
__global__ void k0_chunkmap(const int* __restrict__ ts, const int* __restrict__ chunk_off,
                            int* __restrict__ cmap_e0, int* __restrict__ cmap_rn,
                            int R, int UB) {
    int c = blockIdx.x * blockDim.x + threadIdx.x;
    if (c >= UB) return;
    int T = chunk_off[R];
    if (c >= T) return;
    int lo = 0, hi = R;
    while (hi - lo > 1) {
        int mid = (lo + hi) >> 1;
        if (chunk_off[mid] <= c) lo = mid; else hi = mid;
    }
    int r = lo;
    int e0 = ts[2 * r] + ((c - chunk_off[r]) << 4);
    int n = min(16, ts[2 * r + 1] - e0);
    cmap_e0[c] = e0;
    cmap_rn[c] = (n << 8) | r;
}

// ---------------- prep: W2 -> bf16, transposed to [R][C][H] ------------------------
__global__ void k0_cast(const float* __restrict__ W2, unsigned short* __restrict__ w2t,
                        int total /* R*H*C */) {
    int i = blockIdx.x * blockDim.x + threadIdx.x;
    if (i >= total) return;
    int r = i >> 8;
    int kc = i & 255;
    int k = kc >> 4;
    int c = kc & 15;
    w2t[(r << 8) + (c << 4) + k] = f2bf(W2[i]);
}

// ---------------- Layer 2 via MFMA: one wave = 4 chunks (64 edges) -----------------
// All loads issued upfront as independent chains; 4 independent MFMAs; epilogue is
// pure VALU (shfl-redistributed dsts) + 16 independent pk-bf16 atomics.
__global__ void k3_mfma(const int* __restrict__ srcv, const int* __restrict__ dstv,
                        const int* __restrict__ cmap_e0, const int* __restrict__ cmap_rn,
                        const int* __restrict__ chunk_off,
                        const unsigned short* __restrict__ h1bf,
                        const unsigned short* __restrict__ w2t,
                        unsigned short* __restrict__ acc2, int R) {
    int w = (blockIdx.x * blockDim.x + threadIdx.x) >> 6;
    int l = threadIdx.x & 63;
    int T = chunk_off[R];
    int c0 = w << 2;
    if (c0 >= T) return;

    int rowA = l & 15;
    int kg = l >> 4;

    int e0[4], rr[4], nn[4], s[4], dd[4];
#pragma unroll
    for (int q = 0; q < 4; ++q) {
        int cq = c0 + q;
        bool ok = cq < T;
        int e = ok ? cmap_e0[cq] : 0;
        int rn = ok ? cmap_rn[cq] : 0;
        e0[q] = e;
        rr[q] = rn & 255;
        nn[q] = rn >> 8;             // 0 for invalid chunks
    }
#pragma unroll
    for (int q = 0; q < 4; ++q) {
        int eA = e0[q] + max(0, min(rowA, nn[q] - 1));
        s[q] = srcv[eA];
        dd[q] = dstv[eA];            // lane rowA holds row rowA's dst
    }
    bf16x8 a[4], b[4];
#pragma unroll
    for (int q = 0; q < 4; ++q) {
        bf16x8 z = {0, 0, 0, 0, 0, 0, 0, 0};
        a[q] = z; b[q] = z;
        if (kg < 2) {
            a[q] = *(const bf16x8*)(h1bf + ((size_t)s[q] << 4) + (kg << 3));
            b[q] = *(const bf16x8*)(w2t + ((size_t)rr[q] << 8) + (rowA << 4) + (kg << 3));
        }
    }
    f32x4 d[4];
#pragma unroll
    for (int q = 0; q < 4; ++q) {
        f32x4 z4 = {0.f, 0.f, 0.f, 0.f};
        d[q] = __builtin_amdgcn_mfma_f32_16x16x32_bf16(a[q], b[q], z4, 0, 0, 0);
    }
    int c = l & 15;
#pragma unroll
    for (int q = 0; q < 4; ++q) {
#pragma unroll
        for (int j = 0; j < 4; ++j) {
            int row = (kg << 2) + j;
            float o = __shfl_xor(d[q][j], 1);          // neighbor column, same row
            int ddv = __shfl(dd[q], row);              // dst of this row (from lane row)
            if (((l & 1) == 0) && row < nn[q]) {
                unsigned pk = ((unsigned)f2bf(o) << 16) | f2bf(d[q][j]);
                pk_atomic_bf16(acc2 + ((size_t)ddv << 4) + c, pk);
            }
        }
    }
}

// ---------------- h2 = h1 @ root2 + acc2 + bias2; row log_softmax ------------------
__global__ void k4_fin2(const unsigned short* __restrict__ h1bf,
                        const unsigned short* __restrict__ acc2,
                        const float* __restrict__ root2, const float* __restrict__ bias2,
                        float* __restrict__ out, int N) {
    int n = blockIdx.x * blockDim.x + threadIdx.x;
    if (n >= N) return;
    const uint4* hp = (const uint4*)(h1bf + (size_t)n * 16);
    uint4 h0 = hp[0], h1 = hp[1];
    float h[16] = {bflo(h0.x), bfhi(h0.x), bflo(h0.y), bfhi(h0.y),
                   bflo(h0.z), bfhi(h0.z), bflo(h0.w), bfhi(h0.w),
                   bflo(h1.x), bfhi(h1.x), bflo(h1.y), bfhi(h1.y),
                   bflo(h1.z), bfhi(h1.z), bflo(h1.w), bfhi(h1.w)};
    const uint4* ap = (const uint4*)(acc2 + (size_t)n * 16);
    uint4 a0 = ap[0], a1 = ap[1];
    float av[16] = {bflo(a0.x), bfhi(a0.x), bflo(a0.y), bfhi(a0.y),
                    bflo(a0.z), bfhi(a0.z), bflo(a0.w), bfhi(a0.w),
                    bflo(a1.x), bfhi(a1.x), bflo(a1.y), bfhi(a1.y),
                    bflo(a1.z), bfhi(a1.z), bflo(a1.w), bfhi(a1.w)};
    float* o = out + (size_t)n * C;
    float z[16];
#pragma unroll
    for (int c = 0; c < 16; ++c) {
        float acc = av[c] + bias2[c];
#pragma unroll
        for (int k = 0; k < 16; ++k) acc += h[k] * root2[k * C + c];
        z[c] = acc;
    }
    float m = z[0];
#pragma unroll
    for (int c = 1; c < 16; ++c) m = fmaxf(m, z[c]);
    float se = 0.f;
#pragma unroll
    for (int c = 0; c < 16; ++c) se += __expf(z[c] - m);
    float lse = m + __logf(se);
#pragma unroll
    for (int c = 0; c < 16; ++c) o[c] = z[c] - lse;
}

extern "C" void kernel_launch(void* const* d_in, const int* in_sizes, int n_in,
                              void* d_out, int out_size, void* d_ws, size_t ws_size,
                              hipStream_t stream) {
    const int*   edge_index   = (const int*)d_in[0];
    const int*   edge_type    = (const int*)d_in[1];
    const int*   tensor_slice = (const int*)d_in[2];
    const float* W1    = (const float*)d_in[3];
    const float* root1 = (const float*)d_in[4];
    const float* bias1 = (const float*)d_in[5];
    const float* W2    = (const float*)d_in[6];
    const float* root2 = (const float*)d_in[7];
    const float* bias2 = (const float*)d_in[8];
    float* out = (float*)d_out;

    const int E = in_sizes[0] / 2;
    const int N = in_sizes[4] / H;           // root1 is N*H
    const int R = in_sizes[2] / 2;           // tensor_slice is [R][2]
    const int* srcv = edge_index;
    const int* dstv = edge_index + E;

    // ws: acc1 bf16[N*16] | h1bf u16[N*16] | w2t u16[R*256] | acc2 bf16[N*16]
    //     | chunk_off int[R+1] | cmap_e0 int[UB] | cmap_rn int[UB]
    const int UB = (E + 15) / 16 + R;        // upper bound on chunk count
    char* p = (char*)d_ws;
    unsigned short* acc1 = (unsigned short*)p;   p += (size_t)N * 16 * 2;
    unsigned short* h1bf = (unsigned short*)p;   p += (size_t)N * 16 * 2;
    unsigned short* w2t = (unsigned short*)p;    p += (size_t)R * 256 * 2;
    unsigned short* acc2 = (unsigned short*)p;   p += (size_t)N * 16 * 2;
    int* chunk_off = (int*)p;                    p += (size_t)(R + 1) * 4;
    p = (char*)(((uintptr_t)p + 15) & ~(uintptr_t)15);
    int* cmap_e0 = (int*)p;                      p += (size_t)UB * 4;
    int* cmap_rn = (int*)p;

    hipMemsetAsync(acc1, 0, (size_t)N * 16 * 2, stream);
    hipMemsetAsync(acc2, 0, (size_t)N * 16 * 2, stream);

    const int B = 256;
    k0_prep<<<1, 64, 0, stream>>>(tensor_slice, chunk_off, R);
    k0_chunkmap<<<(UB + B - 1) / B, B, 0, stream>>>(tensor_slice, chunk_off,
                                                    cmap_e0, cmap_rn, R, UB);
    k0_cast<<<(R * 256 + B - 1) / B, B, 0, stream>>>(W2, w2t, R * 256);
    // layer 1: 8 lanes x 8 edges per group
    long long g1 = ((long long)E + 7) / 8;
    long long t1 = g1 * 8;
    k1_scatter<<<(int)((t1 + B - 1) / B), B, 0, stream>>>(srcv, dstv, edge_type, W1, acc1, E, N);
    int total4 = N * H / 4;
    k2_fin1<<<(total4 + B - 1) / B, B, 0, stream>>>(root1, bias1, acc1,
                                                    (unsigned int*)h1bf, total4);
    // layer 2: 4 chunks per wave
    long long waves = ((long long)UB + 3) / 4;
    long long thr = waves * 64;
    k3_mfma<<<(int)((thr + B - 1) / B), B, 0, stream>>>(srcv, dstv, cmap_e0, cmap_rn,
                                                        chunk_off, h1bf, w2t, acc2, R);
    k4_fin2<<<(N + B - 1) / B, B, 0, stream>>>(h1bf, acc2, root2, bias2, out, N);
}